// Round 15
// baseline (201.290 us; speedup 1.0000x reference)
//
#include <hip/hip_runtime.h>
#include <cstdint>

typedef unsigned short u16;
typedef __bf16 bf16x8 __attribute__((ext_vector_type(8)));
typedef float f32x4 __attribute__((ext_vector_type(4)));
typedef float f32x2 __attribute__((ext_vector_type(2)));
typedef u16 u16x8 __attribute__((ext_vector_type(8)));
typedef unsigned int u32x4 __attribute__((ext_vector_type(4)));

__device__ __forceinline__ u16 f2bf(float f) {
  union { float f; uint32_t u; } v; v.f = f;
  uint32_t r = v.u + 0x7fffu + ((v.u >> 16) & 1u);
  return (u16)(r >> 16);
}
__device__ __forceinline__ float bf2f(u16 h) {
  union { uint32_t u; float f; } v; v.u = ((uint32_t)h) << 16;
  return v.f;
}
__device__ __forceinline__ unsigned fbits(float f) {
  union { float f; unsigned u; } v; v.f = f; return v.u;
}
// kv-permutation within a 64-token tile: storage pos for kv so that the PV
// B-operand fragment (k=quad*8+hf*4+r <-> kv=32p+16hf+4quad+r) is one b128.
__device__ __forceinline__ int perm64(int kv) {
  return (kv & 32) | ((kv & 12) << 1) | ((kv & 16) >> 2) | (kv & 3);
}

__device__ __forceinline__ void async16(void* lds, const void* g) {
  __builtin_amdgcn_global_load_lds(
      (const __attribute__((address_space(1))) void*)g,
      (__attribute__((address_space(3))) void*)lds, 16, 0, 0);
}

// ---------------- fused casts (one launch) ----------------
__global__ __launch_bounds__(256)
void k_cast_all(const float* __restrict__ x, u16* __restrict__ xb,
                const float* __restrict__ qw, const float* __restrict__ qb,
                u16* __restrict__ wqkv, float* __restrict__ bqkv,
                const float* __restrict__ pw, u16* __restrict__ wproj) {
  const int bid = blockIdx.x, tid = threadIdx.x;
  if (bid < 2048) {
    int i = (bid * 256 + tid) * 8;
    float4 a = *(const float4*)(x + i);
    float4 b = *(const float4*)(x + i + 4);
    u16x8 o;
    o[0] = f2bf(a.x); o[1] = f2bf(a.y); o[2] = f2bf(a.z); o[3] = f2bf(a.w);
    o[4] = f2bf(b.x); o[5] = f2bf(b.y); o[6] = f2bf(b.z); o[7] = f2bf(b.w);
    *(u16x8*)(xb + i) = o;
  } else if (bid < 3584) {
    int idx = (bid - 2048) * 256 + tid;
    int n = idx >> 7;
    int c = (idx & 127) << 3;
    int hh = n / 192;
    int rr = n - hh * 192;
    int dd = rr / 3;
    int comp = rr - dd * 3;
    int np = comp * 1024 + hh * 64 + dd;
    float qs = (comp == 0) ? 0.001953125f : 1.0f;   // 1/512 folded into Q
    const float* src = qw + (size_t)n * 1024 + c;
    float4 a = *(const float4*)src;
    float4 bb = *(const float4*)(src + 4);
    u16x8 o;
    o[0] = f2bf(a.x * qs); o[1] = f2bf(a.y * qs); o[2] = f2bf(a.z * qs); o[3] = f2bf(a.w * qs);
    o[4] = f2bf(bb.x * qs); o[5] = f2bf(bb.y * qs); o[6] = f2bf(bb.z * qs); o[7] = f2bf(bb.w * qs);
    *(u16x8*)(wqkv + (size_t)np * 1024 + c) = o;
    if (c == 0) bqkv[np] = qb[n] * qs;   // Q bias carries 1/512 too
  } else {
    int i = ((bid - 3584) * 256 + tid) * 8;
    float4 a = *(const float4*)(pw + i);
    float4 b = *(const float4*)(pw + i + 4);
    u16x8 o;
    o[0] = f2bf(a.x); o[1] = f2bf(a.y); o[2] = f2bf(a.z); o[3] = f2bf(a.w);
    o[4] = f2bf(b.x); o[5] = f2bf(b.y); o[6] = f2bf(b.z); o[7] = f2bf(b.w);
    *(u16x8*)(wproj + i) = o;
  }
}

// ---------------- 256x256 fine-interleaved 4-phase GEMM ----------------
// R6/R12-verified structure: per phase {4-8 ds_read | 2 global_load_lds |
// barrier | 16 MFMA setprio}, vmcnt(4) only at mid-tile and boundary, each
// targeting loads issued 4 phases earlier. (R13 half-ring variant nulled —
// reverted to this form.)
template<int MODE>
__device__ __forceinline__
void body8(u16* lds, const u16* __restrict__ A, const u16* __restrict__ B,
           const float* __restrict__ bias, u16* __restrict__ C,
           int N, int K, int m0, int n0) {
  const int tid = threadIdx.x;
  const int lane = tid & 63, wid = tid >> 6;
  const int quad = lane >> 4, lm = lane & 15;
  const int wm = (wid & 1) << 7;       // 0 / 128
  const int wn = (wid >> 1) << 6;      // 0 / 64 / 128 / 192
  u16* LA = lds;                       // [2][16384] u16 (32 KB per buffer)
  u16* LB = lds + 32768;               // [2][16384] u16

  const u16* gA[4]; const u16* gB[4];
#pragma unroll
  for (int i = 0; i < 4; i++) {
    int cp = tid + (i << 9);
    int kg = cp >> 8, rr = cp & 255;
    int row = rr ^ ((kg & 3) << 1);
    gA[i] = A + (size_t)(m0 + row) * K + kg * 8;
    gB[i] = B + (size_t)(n0 + row) * K + kg * 8;
  }

  auto stageA = [&](int kt, int dbuf, int ks) {   // one 16KB half = 2 loads/thread
    const int koff = kt << 6;
    u16* d = LA + dbuf * 16384 + tid * 8;
    async16(d + (2 * ks) * 4096,     gA[2 * ks] + koff);
    async16(d + (2 * ks + 1) * 4096, gA[2 * ks + 1] + koff);
  };
  auto stageB = [&](int kt, int dbuf, int ks) {
    const int koff = kt << 6;
    u16* d = LB + dbuf * 16384 + tid * 8;
    async16(d + (2 * ks) * 4096,     gB[2 * ks] + koff);
    async16(d + (2 * ks + 1) * 4096, gB[2 * ks + 1] + koff);
  };

  f32x4 acc[8][4] = {};
  bf16x8 a[4], b[4];

  auto rdA = [&](int buf, int mh, int ks) {       // 4 x ds_read_b128
    const u16* base = LA + buf * 16384;
#pragma unroll
    for (int mi = 0; mi < 4; mi++)
      a[mi] = *(const bf16x8*)&base[((((ks << 2) + quad) << 8) +
          ((wm + (mh << 6) + (mi << 4) + lm) ^ (quad << 1))) * 8];
  };
  auto rdB = [&](int buf, int ks) {               // 4 x ds_read_b128
    const u16* base = LB + buf * 16384;
#pragma unroll
    for (int ni = 0; ni < 4; ni++)
      b[ni] = *(const bf16x8*)&base[((((ks << 2) + quad) << 8) +
          ((wn + (ni << 4) + lm) ^ (quad << 1))) * 8];
  };
  auto mm = [&](int mh) {                         // 16 MFMA, one (mh,ks) cluster
    __builtin_amdgcn_s_setprio(1);
#pragma unroll
    for (int mi = 0; mi < 4; mi++)
#pragma unroll
      for (int ni = 0; ni < 4; ni++)
        acc[(mh << 2) + mi][ni] = __builtin_amdgcn_mfma_f32_16x16x32_bf16(
            a[mi], b[ni], acc[(mh << 2) + mi][ni], 0, 0, 0);
    __builtin_amdgcn_s_setprio(0);
  };

  // prologue: stage all 4 halves of tile 0, license its ks0 halves.
  stageA(0, 0, 0); stageB(0, 0, 0); stageA(0, 0, 1); stageB(0, 0, 1);
  asm volatile("s_waitcnt vmcnt(4)" ::: "memory");
  __builtin_amdgcn_s_barrier();

  for (int t = 0; t < 16; ++t) {
    const int buf = t & 1, nb = buf ^ 1;
    const bool pre = (t < 15);
    // ---- ph0 (mh0, ks0) ----
    rdA(buf, 0, 0); rdB(buf, 0);
    if (pre) stageA(t + 1, nb, 0);
    asm volatile("" ::: "memory");
    __builtin_amdgcn_s_barrier();
    mm(0);
    // ---- ph1 (mh1, ks0) ----
    rdA(buf, 1, 0);
    if (pre) stageB(t + 1, nb, 0);
    asm volatile("" ::: "memory");
    __builtin_amdgcn_s_barrier();
    mm(1);
    // ---- mid license: ks1(t) halves (issued 4 phases ago) ----
    if (pre) { asm volatile("s_waitcnt vmcnt(4)" ::: "memory"); }
    else     { asm volatile("s_waitcnt vmcnt(0)" ::: "memory"); }
    __builtin_amdgcn_s_barrier();
    // ---- ph2 (mh0, ks1) ----
    rdA(buf, 0, 1); rdB(buf, 1);
    if (pre) stageA(t + 1, nb, 1);
    asm volatile("" ::: "memory");
    __builtin_amdgcn_s_barrier();
    mm(0);
    // ---- ph3 (mh1, ks1) ----
    rdA(buf, 1, 1);
    if (pre) stageB(t + 1, nb, 1);
    asm volatile("" ::: "memory");
    __builtin_amdgcn_s_barrier();
    mm(1);
    // ---- boundary license: ks0(t+1) halves (issued 4 phases ago) ----
    if (pre) {
      asm volatile("s_waitcnt vmcnt(4)" ::: "memory");
      __builtin_amdgcn_s_barrier();
    }
  }

  if (MODE == 2) {
#pragma unroll
    for (int mi = 0; mi < 8; mi++) {
#pragma unroll
      for (int r = 0; r < 4; r++) {
        int row = m0 + wm + (mi << 4) + (quad << 2) + r;
        float bv = bias[row];
#pragma unroll
        for (int ni = 0; ni < 4; ni++) {
          int col = n0 + wn + (ni << 4) + lm;
          int colp = (col & ~63) | perm64(col & 63);
          C[(size_t)row * N + colp] = f2bf(acc[mi][ni][r] + bv);
        }
      }
    }
  } else {
#pragma unroll
    for (int mi = 0; mi < 8; mi++) {
#pragma unroll
      for (int ni = 0; ni < 4; ni++) {
        int col = n0 + wn + (ni << 4) + lm;
        float bv = bias[col];
#pragma unroll
        for (int r = 0; r < 4; r++) {
          int row = m0 + wm + (mi << 4) + (quad << 2) + r;
          C[(size_t)row * N + col] = f2bf(acc[mi][ni][r] + bv);
        }
      }
    }
  }
}

// Merged QKV GEMM: blocks [0,128) -> Q|K [4096,2048]; [128,192) -> V^T
// [1024,4096] (Wv @ X^T, per-row bias, kv-permuted cols). 128 KB dynamic LDS.
__global__ __launch_bounds__(512, 2)
void k_gemm_qkv8(const u16* __restrict__ xb, const u16* __restrict__ wqkv,
                 const float* __restrict__ bqkv, u16* __restrict__ qkb2,
                 u16* __restrict__ vT) {
  extern __shared__ u16 lds[];
  const int bid = blockIdx.x;
  if (bid < 128) {
    body8<0>(lds, xb, wqkv, bqkv, qkb2, 2048, 1024,
             (bid & 15) << 8, (bid >> 4) << 8);
  } else {
    const int v = bid - 128;
    body8<2>(lds, wqkv + (size_t)2048 * 1024, xb, bqkv + 2048, vT,
             4096, 1024, (v & 3) << 8, (v >> 2) << 8);
  }
}

// ---------------- gemm2e: out = po @ wproj^T + bias (fine-interleave) --------
// R14: R6-rhythm port at BM=BN=128, BK=64, 256 thr = 4 waves (2x2, 64x64
// each), grid 32x8 = 256 blocks = 1/CU FULL coverage. LDS 64 KB static
// (2 buf x 16KB A + 16KB B). Per phase {2-6 ds_read | 2-load stage | barrier
// | 8 MFMA setprio}; counted vmcnt(4) at mid/boundary only (loads 4+ phases
// old). Same sequential-k FP accumulation as the old gemm2d -> absmax same.
__global__ __launch_bounds__(256)
void k_gemm2e(const u16* __restrict__ po, const u16* __restrict__ B,
              const float* __restrict__ bias, float* __restrict__ out) {
  __shared__ u16 LA[2][8192];
  __shared__ u16 LB[2][8192];
  const int tid = threadIdx.x;
  const int lane = tid & 63, wid = tid >> 6;
  const int quad = lane >> 4, lm = lane & 15;
  const int wm = (wid & 1) << 6;   // 0 / 64
  const int wn = (wid >> 1) << 6;  // 0 / 64
  const int m0 = blockIdx.y << 7, n0 = blockIdx.x << 7;

  // chunk cp = tid + i*256: kg = cp>>7 (k-group 0..7), rr = cp&127,
  // global row = rr ^ ((kg&3)<<1). i in {0,1} -> ks0 (kg 0..3); {2,3} -> ks1.
  const u16* gA[4]; const u16* gB[4];
#pragma unroll
  for (int i = 0; i < 4; i++) {
    int cp = tid + (i << 8);
    int kg = cp >> 7, rr = cp & 127;
    int row = rr ^ ((kg & 3) << 1);
    gA[i] = po + (size_t)(m0 + row) * 1024 + kg * 8;
    gB[i] = B + (size_t)(n0 + row) * 1024 + kg * 8;
  }

  auto stA = [&](int kt, int dbuf, int ks) {   // one 8KB half = 2 loads/thread
    const int koff = kt << 6;
    u16* d = &LA[dbuf][tid * 8];
    async16(d + (2 * ks) * 2048,     gA[2 * ks] + koff);
    async16(d + (2 * ks + 1) * 2048, gA[2 * ks + 1] + koff);
  };
  auto stB = [&](int kt, int dbuf, int ks) {
    const int koff = kt << 6;
    u16* d = &LB[dbuf][tid * 8];
    async16(d + (2 * ks) * 2048,     gB[2 * ks] + koff);
    async16(d + (2 * ks + 1) * 2048, gB[2 * ks + 1] + koff);
  };

  f32x4 acc[4][4] = {};
  bf16x8 a[2], b[4];

  auto rdA = [&](int buf, int mh, int ks) {    // 2 x ds_read_b128 (mi = 2mh+j)
    const u16* base = LA[buf];
#pragma unroll
    for (int j = 0; j < 2; j++)
      a[j] = *(const bf16x8*)&base[((((ks << 2) + quad) << 7) +
          ((wm + (((mh << 1) + j) << 4) + lm) ^ (quad << 1))) * 8];
  };
  auto rdB = [&](int buf, int ks) {            // 4 x ds_read_b128
    const u16* base = LB[buf];
#pragma unroll
    for (int ni = 0; ni < 4; ni++)
      b[ni] = *(const bf16x8*)&base[((((ks << 2) + quad) << 7) +
          ((wn + (ni << 4) + lm) ^ (quad << 1))) * 8];
  };
  auto mm = [&](int mh) {                      // 8 MFMA
    __builtin_amdgcn_s_setprio(1);
#pragma unroll
    for (int j = 0; j < 2; j++)
#pragma unroll
      for (int ni = 0; ni < 4; ni++)
        acc[(mh << 1) + j][ni] = __builtin_amdgcn_mfma_f32_16x16x32_bf16(
            a[j], b[ni], acc[(mh << 1) + j][ni], 0, 0, 0);
    __builtin_amdgcn_s_setprio(0);
  };

  // prologue: stage all 4 halves of tile 0, license its ks0 halves.
  stA(0, 0, 0); stB(0, 0, 0); stA(0, 0, 1); stB(0, 0, 1);
  asm volatile("s_waitcnt vmcnt(4)" ::: "memory");
  __builtin_amdgcn_s_barrier();

  for (int t = 0; t < 16; ++t) {
    const int buf = t & 1, nb = buf ^ 1;
    const bool pre = (t < 15);
    // ---- ph0 (mh0, ks0) ----
    rdA(buf, 0, 0); rdB(buf, 0);
    if (pre) stA(t + 1, nb, 0);
    asm volatile("" ::: "memory");
    __builtin_amdgcn_s_barrier();
    mm(0);
    // ---- ph1 (mh1, ks0) ----
    rdA(buf, 1, 0);
    if (pre) stB(t + 1, nb, 0);
    asm volatile("" ::: "memory");
    __builtin_amdgcn_s_barrier();
    mm(1);
    // ---- mid license: ks1(t) halves ----
    if (pre) { asm volatile("s_waitcnt vmcnt(4)" ::: "memory"); }
    else     { asm volatile("s_waitcnt vmcnt(0)" ::: "memory"); }
    __builtin_amdgcn_s_barrier();
    // ---- ph2 (mh0, ks1) ----
    rdA(buf, 0, 1); rdB(buf, 1);
    if (pre) stA(t + 1, nb, 1);
    asm volatile("" ::: "memory");
    __builtin_amdgcn_s_barrier();
    mm(0);
    // ---- ph3 (mh1, ks1) ----
    rdA(buf, 1, 1);
    if (pre) stB(t + 1, nb, 1);
    asm volatile("" ::: "memory");
    __builtin_amdgcn_s_barrier();
    mm(1);
    // ---- boundary license: ks0(t+1) halves ----
    if (pre) {
      asm volatile("s_waitcnt vmcnt(4)" ::: "memory");
      __builtin_amdgcn_s_barrier();
    }
  }

#pragma unroll
  for (int mi = 0; mi < 4; mi++) {
#pragma unroll
    for (int r = 0; r < 4; r++) {
      int row = m0 + wm + (mi << 4) + (quad << 2) + r;
#pragma unroll
      for (int ni = 0; ni < 4; ni++) {
        int col = n0 + wn + (ni << 4) + lm;
        out[(size_t)row * 1024 + col] = acc[mi][ni][r] + bias[col];
      }
    }
  }
}

// ---------------- fused attention (all-DMA staging, S^T trick) ----------------
// R12-verified: depth-2 K/V prefetch (3 buffers, counted vmcnt(2), raw
// barriers); softmax on f32x2 pk-fma; row-sum via ones-MFMA (lsacc[r] =
// rowsum for q-row quad*4+r — no epilogue shfls). 512 thr = 8 waves x 16
// q-rows, full kv-sweep, normalized write.
__global__ __launch_bounds__(512, 4)
void k_flash(const u16* __restrict__ qk, const u16* __restrict__ vt,
             u16* __restrict__ po) {
  __shared__ u16 Kl[3][4096];
  __shared__ u16 Vt[3][4096];
  const int tid = threadIdx.x;
  const int lane = tid & 63, wid = tid >> 6;
  const int quad = lane >> 4, lm = lane & 15;
  const int b = blockIdx.y >> 4, h = blockIdx.y & 15;
  const size_t rb = (size_t)b * 2048;
  const int q0 = blockIdx.x << 7;
  const u16* Qg = qk + (rb + q0) * 2048 + h * 64;
  const u16* Kg = qk + rb * 2048 + 1024 + h * 64;
  const u16* Vg = vt + (size_t)(h * 64) * 4096 + rb;

  bf16x8 qf[2];
#pragma unroll
  for (int kq = 0; kq < 2; kq++)
    qf[kq] = *(const bf16x8*)(Qg + (size_t)(wid * 16 + lm) * 2048 + kq * 32 + quad * 8);

  const u16x8 ones_u = {0x3F80, 0x3F80, 0x3F80, 0x3F80, 0x3F80, 0x3F80, 0x3F80, 0x3F80};
  const bf16x8 onesv = *(const bf16x8*)&ones_u;

  f32x4 acc[4] = {};
  f32x4 lsacc = {};

  const int r0 = tid >> 3, c0 = (tid & 7) ^ (r0 & 7);
  const u16* pK = Kg + (size_t)r0 * 2048 + c0 * 8;
  const u16* pV = Vg + (size_t)r0 * 4096 + c0 * 8;
  constexpr size_t KSTEP = (size_t)64 * 2048;

  async16(&Kl[0][tid * 8], pK);
  async16(&Vt[0][tid * 8], pV);
  async16(&Kl[1][tid * 8], pK + KSTEP);
  async16(&Vt[1][tid * 8], pV + 64);
  asm volatile("s_waitcnt vmcnt(2)" ::: "memory");
  __builtin_amdgcn_s_barrier();
  asm volatile("" ::: "memory");

  for (int t = 0; t < 32; t++) {
    const int cur = t - (t / 3) * 3;           // t % 3
    if (t < 30) {
      const int nb2 = (t + 2) - ((t + 2) / 3) * 3;
      async16(&Kl[nb2][tid * 8], pK + (size_t)(t + 2) * KSTEP);
      async16(&Vt[nb2][tid * 8], pV + (size_t)(t + 2) * 64);
    }

    bf16x8 kf[4][2];
#pragma unroll
    for (int n = 0; n < 4; n++)
#pragma unroll
      for (int kq = 0; kq < 2; kq++)
        kf[n][kq] = *(const bf16x8*)&Kl[cur][((n * 16 + lm) * 8 + (((kq << 2) + quad) ^ (lm & 7))) * 8];

    f32x4 s[4] = {};
    __builtin_amdgcn_s_setprio(1);
#pragma unroll
    for (int n = 0; n < 4; n++)
#pragma unroll
      for (int kq = 0; kq < 2; kq++)
        s[n] = __builtin_amdgcn_mfma_f32_16x16x32_bf16(kf[n][kq], qf[kq], s[n], 0, 0, 0);
    __builtin_amdgcn_s_setprio(0);

    u32x4 pa[2];
    const f32x2 h2 = {0.5f, 0.5f}, o2 = {1.0f, 1.0f};
#pragma unroll
    for (int p = 0; p < 2; p++) {
#pragma unroll
      for (int hf = 0; hf < 2; hf++) {
        f32x4 sv = s[2 * p + hf];
        f32x2 lo = __builtin_shufflevector(sv, sv, 0, 1);
        f32x2 hi = __builtin_shufflevector(sv, sv, 2, 3);
        f32x2 plo = __builtin_elementwise_fma(lo, __builtin_elementwise_fma(lo, h2, o2), o2);
        f32x2 phi = __builtin_elementwise_fma(hi, __builtin_elementwise_fma(hi, h2, o2), o2);
        pa[p][hf * 2 + 0] = __builtin_amdgcn_perm(fbits(plo[1]), fbits(plo[0]), 0x07060302u);
        pa[p][hf * 2 + 1] = __builtin_amdgcn_perm(fbits(phi[1]), fbits(phi[0]), 0x07060302u);
      }
    }

    __builtin_amdgcn_s_setprio(1);
#pragma unroll
    for (int dblk = 0; dblk < 4; dblk++) {
#pragma unroll
      for (int p = 0; p < 2; p++) {
        bf16x8 vf = *(const bf16x8*)&Vt[cur][((dblk * 16 + lm) * 8 + (((p << 2) + quad) ^ (lm & 7))) * 8];
        acc[dblk] = __builtin_amdgcn_mfma_f32_16x16x32_bf16(
            *(const bf16x8*)&pa[p], vf, acc[dblk], 0, 0, 0);
      }
    }
#pragma unroll
    for (int p = 0; p < 2; p++)
      lsacc = __builtin_amdgcn_mfma_f32_16x16x32_bf16(
          *(const bf16x8*)&pa[p], onesv, lsacc, 0, 0, 0);
    __builtin_amdgcn_s_setprio(0);

    asm volatile("" ::: "memory");
    if (t < 30)      { asm volatile("s_waitcnt vmcnt(2)" ::: "memory"); }
    else if (t == 30){ asm volatile("s_waitcnt vmcnt(0)" ::: "memory"); }
    if (t < 31) {
      __builtin_amdgcn_s_barrier();
      asm volatile("" ::: "memory");
    }
  }

#pragma unroll
  for (int r = 0; r < 4; r++) {
    float iv = 1.0f / lsacc[r];
    size_t row = rb + q0 + wid * 16 + (quad << 2) + r;
#pragma unroll
    for (int dblk = 0; dblk < 4; dblk++)
      po[row * 1024 + h * 64 + (dblk << 4) + lm] = f2bf(acc[dblk][r] * iv);
  }
}

extern "C" void kernel_launch(void* const* d_in, const int* in_sizes, int n_in,
                              void* d_out, int out_size, void* d_ws, size_t ws_size,
                              hipStream_t stream) {
  const float* x      = (const float*)d_in[0];
  const float* qkv_w  = (const float*)d_in[1];
  const float* qkv_b  = (const float*)d_in[2];
  const float* proj_w = (const float*)d_in[3];
  const float* proj_b = (const float*)d_in[4];
  float* out = (float*)d_out;
  char* ws = (char*)d_ws;

  u16*   xb    = (u16*)(ws);                 //  8388608 B : x bf16 (dead after gemm_qkv)
  u16*   wqkv  = (u16*)(ws + 8388608);       //  6291456 B : permuted qkv_w bf16 (dead after gemm_qkv)
  u16*   wproj = (u16*)(ws + 14680064);      //  2097152 B : proj_w bf16
  float* bqkv  = (float*)(ws + 16777216);    //    12288 B : permuted qkv_b f32 (Q rows /512)
  u16*   qkb2  = (u16*)(ws + 16842752);      // 16777216 B : Q|K bf16 [4096,2048]
  u16*   vT    = (u16*)(ws + 33619968);      //  8388608 B : V^T bf16 [1024,4096], kv-permuted
  u16*   po    = (u16*)(ws + 42008576);      //  8388608 B : normalized O bf16 [4096,1024]

  // 128 KB dynamic LDS for the fine-interleaved QKV GEMM.
  (void)hipFuncSetAttribute((const void*)k_gemm_qkv8,
                            hipFuncAttributeMaxDynamicSharedMemorySize, 131072);

  k_cast_all<<<4096, 256, 0, stream>>>(x, xb, qkv_w, qkv_b, wqkv, bqkv, proj_w, wproj);
  k_gemm_qkv8<<<192, 512, 131072, stream>>>(xb, wqkv, bqkv, qkb2, vT);
  k_flash<<<dim3(16, 32), 512, 0, stream>>>(qkb2, vT, po);
  k_gemm2e<<<dim3(8, 32), 256, 0, stream>>>(po, wproj, proj_b, out);
}

// Round 16
// 198.692 us; speedup vs baseline: 1.0131x; 1.0131x over previous
//
#include <hip/hip_runtime.h>
#include <cstdint>

typedef unsigned short u16;
typedef __bf16 bf16x8 __attribute__((ext_vector_type(8)));
typedef float f32x4 __attribute__((ext_vector_type(4)));
typedef float f32x2 __attribute__((ext_vector_type(2)));
typedef u16 u16x8 __attribute__((ext_vector_type(8)));
typedef unsigned int u32x4 __attribute__((ext_vector_type(4)));

__device__ __forceinline__ u16 f2bf(float f) {
  union { float f; uint32_t u; } v; v.f = f;
  uint32_t r = v.u + 0x7fffu + ((v.u >> 16) & 1u);
  return (u16)(r >> 16);
}
__device__ __forceinline__ float bf2f(u16 h) {
  union { uint32_t u; float f; } v; v.u = ((uint32_t)h) << 16;
  return v.f;
}
__device__ __forceinline__ unsigned fbits(float f) {
  union { float f; unsigned u; } v; v.f = f; return v.u;
}
// kv-permutation within a 64-token tile: storage pos for kv so that the PV
// B-operand fragment (k=quad*8+hf*4+r <-> kv=32p+16hf+4quad+r) is one b128.
__device__ __forceinline__ int perm64(int kv) {
  return (kv & 32) | ((kv & 12) << 1) | ((kv & 16) >> 2) | (kv & 3);
}

__device__ __forceinline__ void async16(void* lds, const void* g) {
  __builtin_amdgcn_global_load_lds(
      (const __attribute__((address_space(1))) void*)g,
      (__attribute__((address_space(3))) void*)lds, 16, 0, 0);
}

// ---------------- fused casts (one launch) ----------------
__global__ __launch_bounds__(256)
void k_cast_all(const float* __restrict__ x, u16* __restrict__ xb,
                const float* __restrict__ qw, const float* __restrict__ qb,
                u16* __restrict__ wqkv, float* __restrict__ bqkv,
                const float* __restrict__ pw, u16* __restrict__ wproj) {
  const int bid = blockIdx.x, tid = threadIdx.x;
  if (bid < 2048) {
    int i = (bid * 256 + tid) * 8;
    float4 a = *(const float4*)(x + i);
    float4 b = *(const float4*)(x + i + 4);
    u16x8 o;
    o[0] = f2bf(a.x); o[1] = f2bf(a.y); o[2] = f2bf(a.z); o[3] = f2bf(a.w);
    o[4] = f2bf(b.x); o[5] = f2bf(b.y); o[6] = f2bf(b.z); o[7] = f2bf(b.w);
    *(u16x8*)(xb + i) = o;
  } else if (bid < 3584) {
    int idx = (bid - 2048) * 256 + tid;
    int n = idx >> 7;
    int c = (idx & 127) << 3;
    int hh = n / 192;
    int rr = n - hh * 192;
    int dd = rr / 3;
    int comp = rr - dd * 3;
    int np = comp * 1024 + hh * 64 + dd;
    float qs = (comp == 0) ? 0.001953125f : 1.0f;   // 1/512 folded into Q
    const float* src = qw + (size_t)n * 1024 + c;
    float4 a = *(const float4*)src;
    float4 bb = *(const float4*)(src + 4);
    u16x8 o;
    o[0] = f2bf(a.x * qs); o[1] = f2bf(a.y * qs); o[2] = f2bf(a.z * qs); o[3] = f2bf(a.w * qs);
    o[4] = f2bf(bb.x * qs); o[5] = f2bf(bb.y * qs); o[6] = f2bf(bb.z * qs); o[7] = f2bf(bb.w * qs);
    *(u16x8*)(wqkv + (size_t)np * 1024 + c) = o;
    if (c == 0) bqkv[np] = qb[n] * qs;   // Q bias carries 1/512 too
  } else {
    int i = ((bid - 3584) * 256 + tid) * 8;
    float4 a = *(const float4*)(pw + i);
    float4 b = *(const float4*)(pw + i + 4);
    u16x8 o;
    o[0] = f2bf(a.x); o[1] = f2bf(a.y); o[2] = f2bf(a.z); o[3] = f2bf(a.w);
    o[4] = f2bf(b.x); o[5] = f2bf(b.y); o[6] = f2bf(b.z); o[7] = f2bf(b.w);
    *(u16x8*)(wproj + i) = o;
  }
}

// ---------------- 256x256 fine-interleaved 4-phase GEMM ----------------
// R6/R12-verified structure: per phase {4-8 ds_read | 2 global_load_lds |
// barrier | 16 MFMA setprio}, vmcnt(4) only at mid-tile and boundary, each
// targeting loads issued 4 phases earlier.
template<int MODE>
__device__ __forceinline__
void body8(u16* lds, const u16* __restrict__ A, const u16* __restrict__ B,
           const float* __restrict__ bias, u16* __restrict__ C,
           int N, int K, int m0, int n0) {
  const int tid = threadIdx.x;
  const int lane = tid & 63, wid = tid >> 6;
  const int quad = lane >> 4, lm = lane & 15;
  const int wm = (wid & 1) << 7;       // 0 / 128
  const int wn = (wid >> 1) << 6;      // 0 / 64 / 128 / 192
  u16* LA = lds;                       // [2][16384] u16 (32 KB per buffer)
  u16* LB = lds + 32768;               // [2][16384] u16

  const u16* gA[4]; const u16* gB[4];
#pragma unroll
  for (int i = 0; i < 4; i++) {
    int cp = tid + (i << 9);
    int kg = cp >> 8, rr = cp & 255;
    int row = rr ^ ((kg & 3) << 1);
    gA[i] = A + (size_t)(m0 + row) * K + kg * 8;
    gB[i] = B + (size_t)(n0 + row) * K + kg * 8;
  }

  auto stageA = [&](int kt, int dbuf, int ks) {   // one 16KB half = 2 loads/thread
    const int koff = kt << 6;
    u16* d = LA + dbuf * 16384 + tid * 8;
    async16(d + (2 * ks) * 4096,     gA[2 * ks] + koff);
    async16(d + (2 * ks + 1) * 4096, gA[2 * ks + 1] + koff);
  };
  auto stageB = [&](int kt, int dbuf, int ks) {
    const int koff = kt << 6;
    u16* d = LB + dbuf * 16384 + tid * 8;
    async16(d + (2 * ks) * 4096,     gB[2 * ks] + koff);
    async16(d + (2 * ks + 1) * 4096, gB[2 * ks + 1] + koff);
  };

  f32x4 acc[8][4] = {};
  bf16x8 a[4], b[4];

  auto rdA = [&](int buf, int mh, int ks) {       // 4 x ds_read_b128
    const u16* base = LA + buf * 16384;
#pragma unroll
    for (int mi = 0; mi < 4; mi++)
      a[mi] = *(const bf16x8*)&base[((((ks << 2) + quad) << 8) +
          ((wm + (mh << 6) + (mi << 4) + lm) ^ (quad << 1))) * 8];
  };
  auto rdB = [&](int buf, int ks) {               // 4 x ds_read_b128
    const u16* base = LB + buf * 16384;
#pragma unroll
    for (int ni = 0; ni < 4; ni++)
      b[ni] = *(const bf16x8*)&base[((((ks << 2) + quad) << 8) +
          ((wn + (ni << 4) + lm) ^ (quad << 1))) * 8];
  };
  auto mm = [&](int mh) {                         // 16 MFMA, one (mh,ks) cluster
    __builtin_amdgcn_s_setprio(1);
#pragma unroll
    for (int mi = 0; mi < 4; mi++)
#pragma unroll
      for (int ni = 0; ni < 4; ni++)
        acc[(mh << 2) + mi][ni] = __builtin_amdgcn_mfma_f32_16x16x32_bf16(
            a[mi], b[ni], acc[(mh << 2) + mi][ni], 0, 0, 0);
    __builtin_amdgcn_s_setprio(0);
  };

  // prologue: stage all 4 halves of tile 0, license its ks0 halves.
  stageA(0, 0, 0); stageB(0, 0, 0); stageA(0, 0, 1); stageB(0, 0, 1);
  asm volatile("s_waitcnt vmcnt(4)" ::: "memory");
  __builtin_amdgcn_s_barrier();

  for (int t = 0; t < 16; ++t) {
    const int buf = t & 1, nb = buf ^ 1;
    const bool pre = (t < 15);
    // ---- ph0 (mh0, ks0) ----
    rdA(buf, 0, 0); rdB(buf, 0);
    if (pre) stageA(t + 1, nb, 0);
    asm volatile("" ::: "memory");
    __builtin_amdgcn_s_barrier();
    mm(0);
    // ---- ph1 (mh1, ks0) ----
    rdA(buf, 1, 0);
    if (pre) stageB(t + 1, nb, 0);
    asm volatile("" ::: "memory");
    __builtin_amdgcn_s_barrier();
    mm(1);
    // ---- mid license: ks1(t) halves (issued 4 phases ago) ----
    if (pre) { asm volatile("s_waitcnt vmcnt(4)" ::: "memory"); }
    else     { asm volatile("s_waitcnt vmcnt(0)" ::: "memory"); }
    __builtin_amdgcn_s_barrier();
    // ---- ph2 (mh0, ks1) ----
    rdA(buf, 0, 1); rdB(buf, 1);
    if (pre) stageA(t + 1, nb, 1);
    asm volatile("" ::: "memory");
    __builtin_amdgcn_s_barrier();
    mm(0);
    // ---- ph3 (mh1, ks1) ----
    rdA(buf, 1, 1);
    if (pre) stageB(t + 1, nb, 1);
    asm volatile("" ::: "memory");
    __builtin_amdgcn_s_barrier();
    mm(1);
    // ---- boundary license: ks0(t+1) halves (issued 4 phases ago) ----
    if (pre) {
      asm volatile("s_waitcnt vmcnt(4)" ::: "memory");
      __builtin_amdgcn_s_barrier();
    }
  }

  if (MODE == 2) {
#pragma unroll
    for (int mi = 0; mi < 8; mi++) {
#pragma unroll
      for (int r = 0; r < 4; r++) {
        int row = m0 + wm + (mi << 4) + (quad << 2) + r;
        float bv = bias[row];
#pragma unroll
        for (int ni = 0; ni < 4; ni++) {
          int col = n0 + wn + (ni << 4) + lm;
          int colp = (col & ~63) | perm64(col & 63);
          C[(size_t)row * N + colp] = f2bf(acc[mi][ni][r] + bv);
        }
      }
    }
  } else {
#pragma unroll
    for (int mi = 0; mi < 8; mi++) {
#pragma unroll
      for (int ni = 0; ni < 4; ni++) {
        int col = n0 + wn + (ni << 4) + lm;
        float bv = bias[col];
#pragma unroll
        for (int r = 0; r < 4; r++) {
          int row = m0 + wm + (mi << 4) + (quad << 2) + r;
          C[(size_t)row * N + col] = f2bf(acc[mi][ni][r] + bv);
        }
      }
    }
  }
}

// Merged QKV GEMM: blocks [0,128) -> Q|K [4096,2048]; [128,192) -> V^T
// [1024,4096] (Wv @ X^T, per-row bias, kv-permuted cols). 128 KB dynamic LDS.
__global__ __launch_bounds__(512, 2)
void k_gemm_qkv8(const u16* __restrict__ xb, const u16* __restrict__ wqkv,
                 const float* __restrict__ bqkv, u16* __restrict__ qkb2,
                 u16* __restrict__ vT) {
  extern __shared__ u16 lds[];
  const int bid = blockIdx.x;
  if (bid < 128) {
    body8<0>(lds, xb, wqkv, bqkv, qkb2, 2048, 1024,
             (bid & 15) << 8, (bid >> 4) << 8);
  } else {
    const int v = bid - 128;
    body8<2>(lds, wqkv + (size_t)2048 * 1024, xb, bqkv + 2048, vT,
             4096, 1024, (v & 3) << 8, (v >> 2) << 8);
  }
}

// ---------------- gemm2d: out = po @ wproj^T + bias (all-DMA) ----------------
// R9/R12-verified (session-best config): po row-normalized by k_flash; A
// staged via global_load_lds like B. 128x64 tile, grid (16,32).
__global__ __launch_bounds__(256)
void k_gemm2d(const u16* __restrict__ po, const u16* __restrict__ B,
              const float* __restrict__ bias, float* __restrict__ out) {
  __shared__ u16 sA[4096];
  __shared__ u16 sB[2048];
  const int tid = threadIdx.x;
  const int lane = tid & 63, wid = tid >> 6;
  const int quad = lane >> 4, lm = lane & 15;
  const int wm = (wid & 1) << 6, wn = (wid >> 1) << 5;
  const int m0 = blockIdx.y << 7, n0 = blockIdx.x << 6;

  const int ca0 = tid >> 7,         ra0 = (tid & 127) ^ ((ca0 & 3) << 1);
  const int ca1 = (tid + 256) >> 7, ra1 = ((tid + 256) & 127) ^ ((ca1 & 3) << 1);
  const u16* pA0 = po + (size_t)(m0 + ra0) * 1024 + ca0 * 8;
  const u16* pA1 = po + (size_t)(m0 + ra1) * 1024 + ca1 * 8;
  const int cb = tid >> 6, rbw = (tid & 63) ^ ((cb & 3) << 1);
  const u16* gB = B + (size_t)(n0 + rbw) * 1024 + cb * 8;

  f32x4 acc[4][2] = {};

  for (int k0 = 0; k0 < 1024; k0 += 32) {
    __syncthreads();
    async16(&sB[tid * 8], gB + k0);
    async16(&sA[tid * 8], pA0 + k0);
    async16(&sA[(tid + 256) * 8], pA1 + k0);
    asm volatile("s_waitcnt vmcnt(0)" ::: "memory");
    __syncthreads();
    bf16x8 af[4], bfr[2];
#pragma unroll
    for (int mi = 0; mi < 4; mi++)
      af[mi] = *(const bf16x8*)&sA[(quad * 128 + ((wm + (mi << 4) + lm) ^ (quad << 1))) * 8];
#pragma unroll
    for (int ni = 0; ni < 2; ni++)
      bfr[ni] = *(const bf16x8*)&sB[(quad * 64 + ((wn + (ni << 4) + lm) ^ (quad << 1))) * 8];
#pragma unroll
    for (int mi = 0; mi < 4; mi++)
#pragma unroll
      for (int ni = 0; ni < 2; ni++)
        acc[mi][ni] = __builtin_amdgcn_mfma_f32_16x16x32_bf16(af[mi], bfr[ni], acc[mi][ni], 0, 0, 0);
  }

#pragma unroll
  for (int mi = 0; mi < 4; mi++) {
#pragma unroll
    for (int r = 0; r < 4; r++) {
      int row = m0 + wm + (mi << 4) + (quad << 2) + r;
#pragma unroll
      for (int ni = 0; ni < 2; ni++) {
        int col = n0 + wn + (ni << 4) + lm;
        out[(size_t)row * 1024 + col] = acc[mi][ni][r] + bias[col];
      }
    }
  }
}

// ---------------- fused attention (all-DMA staging, S^T trick) ----------------
// R12-verified: depth-2 K/V prefetch (3 buffers, counted vmcnt(2), raw
// barriers); softmax on f32x2 pk-fma; row-sum via ones-MFMA (lsacc[r] =
// rowsum for q-row quad*4+r — no epilogue shfls). 512 thr = 8 waves x 16
// q-rows, full kv-sweep, normalized write.
__global__ __launch_bounds__(512, 4)
void k_flash(const u16* __restrict__ qk, const u16* __restrict__ vt,
             u16* __restrict__ po) {
  __shared__ u16 Kl[3][4096];
  __shared__ u16 Vt[3][4096];
  const int tid = threadIdx.x;
  const int lane = tid & 63, wid = tid >> 6;
  const int quad = lane >> 4, lm = lane & 15;
  const int b = blockIdx.y >> 4, h = blockIdx.y & 15;
  const size_t rb = (size_t)b * 2048;
  const int q0 = blockIdx.x << 7;
  const u16* Qg = qk + (rb + q0) * 2048 + h * 64;
  const u16* Kg = qk + rb * 2048 + 1024 + h * 64;
  const u16* Vg = vt + (size_t)(h * 64) * 4096 + rb;

  bf16x8 qf[2];
#pragma unroll
  for (int kq = 0; kq < 2; kq++)
    qf[kq] = *(const bf16x8*)(Qg + (size_t)(wid * 16 + lm) * 2048 + kq * 32 + quad * 8);

  const u16x8 ones_u = {0x3F80, 0x3F80, 0x3F80, 0x3F80, 0x3F80, 0x3F80, 0x3F80, 0x3F80};
  const bf16x8 onesv = *(const bf16x8*)&ones_u;

  f32x4 acc[4] = {};
  f32x4 lsacc = {};

  const int r0 = tid >> 3, c0 = (tid & 7) ^ (r0 & 7);
  const u16* pK = Kg + (size_t)r0 * 2048 + c0 * 8;
  const u16* pV = Vg + (size_t)r0 * 4096 + c0 * 8;
  constexpr size_t KSTEP = (size_t)64 * 2048;

  async16(&Kl[0][tid * 8], pK);
  async16(&Vt[0][tid * 8], pV);
  async16(&Kl[1][tid * 8], pK + KSTEP);
  async16(&Vt[1][tid * 8], pV + 64);
  asm volatile("s_waitcnt vmcnt(2)" ::: "memory");
  __builtin_amdgcn_s_barrier();
  asm volatile("" ::: "memory");

  for (int t = 0; t < 32; t++) {
    const int cur = t - (t / 3) * 3;           // t % 3
    if (t < 30) {
      const int nb2 = (t + 2) - ((t + 2) / 3) * 3;
      async16(&Kl[nb2][tid * 8], pK + (size_t)(t + 2) * KSTEP);
      async16(&Vt[nb2][tid * 8], pV + (size_t)(t + 2) * 64);
    }

    bf16x8 kf[4][2];
#pragma unroll
    for (int n = 0; n < 4; n++)
#pragma unroll
      for (int kq = 0; kq < 2; kq++)
        kf[n][kq] = *(const bf16x8*)&Kl[cur][((n * 16 + lm) * 8 + (((kq << 2) + quad) ^ (lm & 7))) * 8];

    f32x4 s[4] = {};
    __builtin_amdgcn_s_setprio(1);
#pragma unroll
    for (int n = 0; n < 4; n++)
#pragma unroll
      for (int kq = 0; kq < 2; kq++)
        s[n] = __builtin_amdgcn_mfma_f32_16x16x32_bf16(kf[n][kq], qf[kq], s[n], 0, 0, 0);
    __builtin_amdgcn_s_setprio(0);

    u32x4 pa[2];
    const f32x2 h2 = {0.5f, 0.5f}, o2 = {1.0f, 1.0f};
#pragma unroll
    for (int p = 0; p < 2; p++) {
#pragma unroll
      for (int hf = 0; hf < 2; hf++) {
        f32x4 sv = s[2 * p + hf];
        f32x2 lo = __builtin_shufflevector(sv, sv, 0, 1);
        f32x2 hi = __builtin_shufflevector(sv, sv, 2, 3);
        f32x2 plo = __builtin_elementwise_fma(lo, __builtin_elementwise_fma(lo, h2, o2), o2);
        f32x2 phi = __builtin_elementwise_fma(hi, __builtin_elementwise_fma(hi, h2, o2), o2);
        pa[p][hf * 2 + 0] = __builtin_amdgcn_perm(fbits(plo[1]), fbits(plo[0]), 0x07060302u);
        pa[p][hf * 2 + 1] = __builtin_amdgcn_perm(fbits(phi[1]), fbits(phi[0]), 0x07060302u);
      }
    }

    __builtin_amdgcn_s_setprio(1);
#pragma unroll
    for (int dblk = 0; dblk < 4; dblk++) {
#pragma unroll
      for (int p = 0; p < 2; p++) {
        bf16x8 vf = *(const bf16x8*)&Vt[cur][((dblk * 16 + lm) * 8 + (((p << 2) + quad) ^ (lm & 7))) * 8];
        acc[dblk] = __builtin_amdgcn_mfma_f32_16x16x32_bf16(
            *(const bf16x8*)&pa[p], vf, acc[dblk], 0, 0, 0);
      }
    }
#pragma unroll
    for (int p = 0; p < 2; p++)
      lsacc = __builtin_amdgcn_mfma_f32_16x16x32_bf16(
          *(const bf16x8*)&pa[p], onesv, lsacc, 0, 0, 0);
    __builtin_amdgcn_s_setprio(0);

    asm volatile("" ::: "memory");
    if (t < 30)      { asm volatile("s_waitcnt vmcnt(2)" ::: "memory"); }
    else if (t == 30){ asm volatile("s_waitcnt vmcnt(0)" ::: "memory"); }
    if (t < 31) {
      __builtin_amdgcn_s_barrier();
      asm volatile("" ::: "memory");
    }
  }

#pragma unroll
  for (int r = 0; r < 4; r++) {
    float iv = 1.0f / lsacc[r];
    size_t row = rb + q0 + wid * 16 + (quad << 2) + r;
#pragma unroll
    for (int dblk = 0; dblk < 4; dblk++)
      po[row * 1024 + h * 64 + (dblk << 4) + lm] = f2bf(acc[dblk][r] * iv);
  }
}

extern "C" void kernel_launch(void* const* d_in, const int* in_sizes, int n_in,
                              void* d_out, int out_size, void* d_ws, size_t ws_size,
                              hipStream_t stream) {
  const float* x      = (const float*)d_in[0];
  const float* qkv_w  = (const float*)d_in[1];
  const float* qkv_b  = (const float*)d_in[2];
  const float* proj_w = (const float*)d_in[3];
  const float* proj_b = (const float*)d_in[4];
  float* out = (float*)d_out;
  char* ws = (char*)d_ws;

  u16*   xb    = (u16*)(ws);                 //  8388608 B : x bf16 (dead after gemm_qkv)
  u16*   wqkv  = (u16*)(ws + 8388608);       //  6291456 B : permuted qkv_w bf16 (dead after gemm_qkv)
  u16*   wproj = (u16*)(ws + 14680064);      //  2097152 B : proj_w bf16
  float* bqkv  = (float*)(ws + 16777216);    //    12288 B : permuted qkv_b f32 (Q rows /512)
  u16*   qkb2  = (u16*)(ws + 16842752);      // 16777216 B : Q|K bf16 [4096,2048]
  u16*   vT    = (u16*)(ws + 33619968);      //  8388608 B : V^T bf16 [1024,4096], kv-permuted
  u16*   po    = (u16*)(ws + 42008576);      //  8388608 B : normalized O bf16 [4096,1024]

  // 128 KB dynamic LDS for the fine-interleaved QKV GEMM.
  (void)hipFuncSetAttribute((const void*)k_gemm_qkv8,
                            hipFuncAttributeMaxDynamicSharedMemorySize, 131072);

  k_cast_all<<<4096, 256, 0, stream>>>(x, xb, qkv_w, qkv_b, wqkv, bqkv, proj_w, wproj);
  k_gemm_qkv8<<<192, 512, 131072, stream>>>(xb, wqkv, bqkv, qkb2, vT);
  k_flash<<<dim3(16, 32), 512, 0, stream>>>(qkb2, vT, po);
  k_gemm2d<<<dim3(16, 32), 256, 0, stream>>>(po, wproj, proj_b, out);
}